// Round 21
// baseline (421.892 us; speedup 1.0000x reference)
//
#include <hip/hip_runtime.h>
#include <hip/hip_bf16.h>

#define DEV static __device__ __forceinline__

typedef unsigned short u16;
typedef float fp32x4 __attribute__((ext_vector_type(4)));
typedef short bf16x8 __attribute__((ext_vector_type(8)));
typedef short bf16x4 __attribute__((ext_vector_type(4)));

DEV float bf2f(u16 u) { return __uint_as_float(((unsigned)u) << 16); }
DEV u16 f2bf(float f) {
  unsigned x = __float_as_uint(f);
  x += 0x7fffu + ((x >> 16) & 1u);
  return (u16)(x >> 16);
}

// packed f32x2 -> bf16x2 (low = a, high = b); no builtin on gfx950 (m240)
DEV unsigned cvt_pk_bf16(float a, float b) {
  unsigned r;
  asm("v_cvt_pk_bf16_f32 %0, %1, %2" : "=v"(r) : "v"(a), "v"(b));
  return r;
}

DEV void gload_lds16(const void* g, void* l) {
  __builtin_amdgcn_global_load_lds(
      (__attribute__((address_space(1))) void*)(unsigned long long)g,
      (__attribute__((address_space(3))) void*)(unsigned int)(unsigned long long)l,
      16, 0, 0);
}

// ---------------- fp32 -> bf16 convert: ALL weights in one dispatch ---------
__global__ __launch_bounds__(256) void cvt_all(
    const float* __restrict__ wq, const float* __restrict__ wk,
    const float* __restrict__ wv, const float* __restrict__ wo,
    const float* __restrict__ w1, const float* __restrict__ w2,
    u16* __restrict__ dst) {
  const size_t i = (size_t)blockIdx.x * 256 + threadIdx.x;  // vec4 index
  const size_t e = i * 4;                                   // element index
  const float* src;
  size_t off;
  const size_t M1 = 1u << 20;
  if (e < M1) { src = wq; off = e; }
  else if (e < 2 * M1) { src = wk; off = e - M1; }
  else if (e < 3 * M1) { src = wv; off = e - 2 * M1; }
  else if (e < 4 * M1) { src = wo; off = e - 3 * M1; }
  else if (e < 8 * M1) { src = w1; off = e - 4 * M1; }
  else { src = w2; off = e - 8 * M1; }
  const fp32x4 v = *(const fp32x4*)(src + off);
  bf16x4 o;
#pragma unroll
  for (int j = 0; j < 4; j++) o[j] = (short)f2bf(v[j]);
  ((bf16x4*)dst)[i] = o;
}

// ---------------- LayerNorm (ddof=1, eps added to std), fp32 in -> bf16 out --
__global__ __launch_bounds__(256) void ln_kernel(const float* __restrict__ x,
                                                 u16* __restrict__ y,
                                                 const float* __restrict__ gamma,
                                                 const float* __restrict__ beta) {
  const int row = blockIdx.x;
  const int t = threadIdx.x;
  const fp32x4 v = ((const fp32x4*)(x + (size_t)row * 1024))[t];
  float s = v[0] + v[1] + v[2] + v[3];
  float ss = v[0] * v[0] + v[1] * v[1] + v[2] * v[2] + v[3] * v[3];
#pragma unroll
  for (int o = 32; o > 0; o >>= 1) {
    s += __shfl_down(s, o);
    ss += __shfl_down(ss, o);
  }
  __shared__ float rs[4], rss[4];
  const int w = t >> 6;
  if ((t & 63) == 0) { rs[w] = s; rss[w] = ss; }
  __syncthreads();
  const float S = rs[0] + rs[1] + rs[2] + rs[3];
  const float SS = rss[0] + rss[1] + rss[2] + rss[3];
  const float mean = S * (1.0f / 1024.0f);
  const float var = fmaxf((SS - 1024.0f * mean * mean) * (1.0f / 1023.0f), 0.0f);
  const float sc = gamma[0] / (sqrtf(var) + 1e-6f);
  const float be = beta[0];
  bf16x4 o;
#pragma unroll
  for (int j = 0; j < 4; j++) o[j] = (short)f2bf((v[j] - mean) * sc + be);
  ((bf16x4*)(y + (size_t)row * 1024))[t] = o;
}

// ---------------- LayerNorm, bf16 in -> bf16 out (stats in fp32) ------------
__global__ __launch_bounds__(256) void ln_bf16_kernel(const u16* __restrict__ x,
                                                      u16* __restrict__ y,
                                                      const float* __restrict__ gamma,
                                                      const float* __restrict__ beta) {
  const int row = blockIdx.x;
  const int t = threadIdx.x;
  const bf16x4 vb = ((const bf16x4*)(x + (size_t)row * 1024))[t];
  float v0 = bf2f((u16)vb[0]), v1 = bf2f((u16)vb[1]);
  float v2 = bf2f((u16)vb[2]), v3 = bf2f((u16)vb[3]);
  float s = v0 + v1 + v2 + v3;
  float ss = v0 * v0 + v1 * v1 + v2 * v2 + v3 * v3;
#pragma unroll
  for (int o = 32; o > 0; o >>= 1) {
    s += __shfl_down(s, o);
    ss += __shfl_down(ss, o);
  }
  __shared__ float rs[4], rss[4];
  const int w = t >> 6;
  if ((t & 63) == 0) { rs[w] = s; rss[w] = ss; }
  __syncthreads();
  const float S = rs[0] + rs[1] + rs[2] + rs[3];
  const float SS = rss[0] + rss[1] + rss[2] + rss[3];
  const float mean = S * (1.0f / 1024.0f);
  const float var = fmaxf((SS - 1024.0f * mean * mean) * (1.0f / 1023.0f), 0.0f);
  const float sc = gamma[0] / (sqrtf(var) + 1e-6f);
  const float be = beta[0];
  bf16x4 o;
  o[0] = (short)f2bf((v0 - mean) * sc + be);
  o[1] = (short)f2bf((v1 - mean) * sc + be);
  o[2] = (short)f2bf((v2 - mean) * sc + be);
  o[3] = (short)f2bf((v3 - mean) * sc + be);
  ((bf16x4*)(y + (size_t)row * 1024))[t] = o;
}

// ---------------- GEMM: C[M,N] = A[M,K] @ W[N,K]^T (BK=64 m97 skeleton) -----
// BK=64 halves barrier-drain events vs BK=32 (R19 win). Frag reads use
// both-sides XOR involution (rule 21) -> 2-way = free.
// EPI: 1 = bias+relu -> bf16; 4 = fused QKV (Q,K direct; V -> VT layout);
//      5 = +fp32 resid -> bf16 store; 6 = bias + bf16 resid -> fp32 store
template <int EPI>
__global__ __launch_bounds__(256, 3) void gemm_bt(
    const u16* __restrict__ A, const u16* __restrict__ W, u16* __restrict__ Cb,
    float* __restrict__ Cf, const float* __restrict__ bias,
    const float* __restrict__ resid, int M, int N, int K,
    u16* __restrict__ CbK, u16* __restrict__ CbV, const u16* __restrict__ residB) {
  __shared__ __attribute__((aligned(16))) u16 sA[128 * 64];
  __shared__ __attribute__((aligned(16))) u16 sB[128 * 64];
  const int t = threadIdx.x;
  const int lane = t & 63;
  const int w = t >> 6;
  const int wr = (w >> 1) * 64;
  const int wc = (w & 1) * 64;
  const int lr = lane & 15;
  const int hi = lane >> 4;

  const int nwgx = gridDim.x;
  const int orig = blockIdx.y * nwgx + blockIdx.x;
  const int cpx = (nwgx * gridDim.y) >> 3;
  const int logical = (orig & 7) * cpx + (orig >> 3);
  const int bx = logical % nwgx, by = logical / nwgx;

  const int srow = t >> 3;
  const int lchunk = (t & 7) ^ (srow & 7);
  const u16* gA = A + (size_t)(by * 128 + srow) * K + lchunk * 8;
  const u16* gB = W + (size_t)(bx * 128 + srow) * K + lchunk * 8;
  const size_t rstep32 = (size_t)32 * K;
  u16* lA = &sA[t * 8];
  u16* lB = &sB[t * 8];

  const fp32x4 zero4 = {0.f, 0.f, 0.f, 0.f};
  fp32x4 acc[4][4];
#pragma unroll
  for (int i = 0; i < 4; i++)
#pragma unroll
    for (int j = 0; j < 4; j++) acc[i][j] = zero4;

  for (int k0 = 0; k0 < K; k0 += 64) {
#pragma unroll
    for (int p = 0; p < 4; p++) {
      gload_lds16(gA + p * rstep32, lA + p * 2048);
      gload_lds16(gB + p * rstep32, lB + p * 2048);
    }
    gA += 64;
    gB += 64;
    __syncthreads();
#pragma unroll
    for (int ks = 0; ks < 2; ks++) {
      const int fcA = ((ks * 4 + hi) ^ (lr & 7)) * 8;
      bf16x8 af[4], bfr[4];
#pragma unroll
      for (int i = 0; i < 4; i++)
        af[i] = *(const bf16x8*)&sA[(wr + i * 16 + lr) * 64 + fcA];
#pragma unroll
      for (int j = 0; j < 4; j++)
        bfr[j] = *(const bf16x8*)&sB[(wc + j * 16 + lr) * 64 + fcA];
#pragma unroll
      for (int i = 0; i < 4; i++)
#pragma unroll
        for (int j = 0; j < 4; j++)
          acc[i][j] =
              __builtin_amdgcn_mfma_f32_16x16x32_bf16(af[i], bfr[j], acc[i][j], 0, 0, 0);
    }
    __syncthreads();
  }

  const int row0 = by * 128 + wr + hi * 4;
  const int col0 = bx * 128 + wc + lr;

  if constexpr (EPI == 4) {
    if (col0 < 2048) {  // Q or K block: direct bf16 store
      u16* qkvDst = (col0 >> 10) ? CbK : Cb;
      const int colL0 = col0 & 1023;
#pragma unroll
      for (int i = 0; i < 4; i++)
#pragma unroll
        for (int r = 0; r < 4; r++) {
          const size_t row = (size_t)(row0 + i * 16 + r);
#pragma unroll
          for (int j = 0; j < 4; j++)
            qkvDst[row * 1024 + colL0 + j * 16] = f2bf(acc[i][j][r]);
        }
    } else {
      // V block: per-wave 64x64 in-LDS transpose -> VT[(b*16+h)*64+d][s]
      __shared__ __attribute__((aligned(16))) u16 sT[2][64 * 72];
#pragma unroll
      for (int ph = 0; ph < 2; ++ph) {
        __syncthreads();
        if ((w >> 1) == ph) {
          u16* R = sT[w & 1];
#pragma unroll
          for (int j = 0; j < 4; j++) {
            const int ci = j * 16 + lr;
            const int X = (ci ^ (ci >> 3)) & 7;
#pragma unroll
            for (int i = 0; i < 4; i++)
#pragma unroll
              for (int r = 0; r < 4; r++) {
                const int ri = i * 16 + hi * 4 + r;
                R[ci * 72 + ((((ri >> 3) ^ X) << 3) | (ri & 7))] =
                    f2bf(acc[i][j][r]);
              }
          }
        }
        __syncthreads();
        if ((w >> 1) == ph) {
          const u16* R = sT[w & 1];
          const int ci = lane;
          const int X = (ci ^ (ci >> 3)) & 7;
          const int h = (bx - 16) * 2 + (w & 1);
          const int bidx = by >> 4;
          const int sb_base = (by & 15) * 128 + (w >> 1) * 64;
          u16* vdst = CbV + ((size_t)((bidx * 16 + h) * 64 + ci)) * 2048 + sb_base;
#pragma unroll
          for (int ch = 0; ch < 8; ch++) {
            bf16x8 vv = *(const bf16x8*)&R[ci * 72 + ((ch ^ X) << 3)];
            *(bf16x8*)(vdst + ch * 8) = vv;
          }
        }
      }
    }
    return;
  }

  float bj[4] = {0.f, 0.f, 0.f, 0.f};
  if (EPI == 1 || EPI == 6) {
#pragma unroll
    for (int j = 0; j < 4; j++) bj[j] = bias[col0 + j * 16];
  }
#pragma unroll
  for (int i = 0; i < 4; i++) {
#pragma unroll
    for (int r = 0; r < 4; r++) {
      const size_t row = (size_t)(row0 + i * 16 + r);
#pragma unroll
      for (int j = 0; j < 4; j++) {
        const int col = col0 + j * 16;
        float v = acc[i][j][r];
        if (EPI == 1) {
          v = fmaxf(v + bj[j], 0.f);
          Cb[row * N + col] = f2bf(v);
        } else if (EPI == 5) {
          v += resid[row * N + col];
          Cb[row * N + col] = f2bf(v);
        } else if (EPI == 6) {
          v += bj[j] + bf2f(residB[row * N + col]);
          Cf[row * N + col] = v;
        }
      }
    }
  }
}

// ---------------- Flash attention (64 q-rows/block, 64-k tiles) -------------
// R14-proven internals + NEW: double-buffered sK/sVT -> ONE barrier per k-tile
// (writes to buf[(kt+1)&1] only conflict with iter kt-1's reads of the same
// parity, which the single top-of-loop barrier orders). sQP stays single:
// each wave touches only its own 16 rows for qreg reads and P writes.
DEV int swz(int row, int chunk) { return row * 64 + ((chunk ^ (row & 7)) << 3); }

__global__ __launch_bounds__(256, 2) void attn_kernel(const u16* __restrict__ Q,
                                                      const u16* __restrict__ K,
                                                      const u16* __restrict__ VT,
                                                      u16* __restrict__ O) {
  const int orig = blockIdx.x + 32 * (blockIdx.y + 16 * blockIdx.z);
  const int logical = (orig & 7) * 256 + (orig >> 3);
  const int qt = logical & 31;
  const int h = (logical >> 5) & 15;
  const int b = logical >> 9;

  const int t = threadIdx.x, lane = t & 63, w = t >> 6;
  const int lr = lane & 15, hi = lane >> 4;

  __shared__ u16 sK[2][64 * 64];
  __shared__ u16 sVT[2][64 * 64];
  __shared__ u16 sQP[64 * 64];

  const size_t base = ((size_t)b * 2048) * 1024 + (size_t)h * 64;
  const size_t vbase = (((size_t)b * 16 + h) * 64) * 2048;
  const int r = t >> 2, c0 = (t & 3) * 16;
  const int wch = (t & 3) * 2;

  {
    const float qs = 0.125f * 1.44269504f;
    const u16* src = Q + base + (size_t)(qt * 64 + r) * 1024 + c0;
    bf16x8 u0 = *(const bf16x8*)src;
    bf16x8 u1 = *(const bf16x8*)(src + 8);
    union { unsigned u[4]; bf16x8 v; } q0, q1;
#pragma unroll
    for (int j = 0; j < 4; j++)
      q0.u[j] = cvt_pk_bf16(bf2f((u16)u0[2 * j]) * qs, bf2f((u16)u0[2 * j + 1]) * qs);
#pragma unroll
    for (int j = 0; j < 4; j++)
      q1.u[j] = cvt_pk_bf16(bf2f((u16)u1[2 * j]) * qs, bf2f((u16)u1[2 * j + 1]) * qs);
    *(bf16x8*)&sQP[swz(r, wch)] = q0.v;
    *(bf16x8*)&sQP[swz(r, wch + 1)] = q1.v;
  }
  __syncthreads();
  const int qrow = w * 16 + lr;
  bf16x8 qreg0 = *(const bf16x8*)&sQP[swz(qrow, hi)];
  bf16x8 qreg1 = *(const bf16x8*)&sQP[swz(qrow, 4 + hi)];

  // prologue: tile 0 -> regs -> buf0; tile 1 -> regs
  bf16x8 kA, kB, vA, vB;
  {
    const u16* ks = K + base + (size_t)r * 1024 + c0;
    kA = *(const bf16x8*)ks;
    kB = *(const bf16x8*)(ks + 8);
    const u16* vs = VT + vbase + (size_t)r * 2048 + c0;
    vA = *(const bf16x8*)vs;
    vB = *(const bf16x8*)(vs + 8);
  }
  *(bf16x8*)&sK[0][swz(r, wch)] = kA;
  *(bf16x8*)&sK[0][swz(r, wch + 1)] = kB;
  *(bf16x8*)&sVT[0][swz(r, wch)] = vA;
  *(bf16x8*)&sVT[0][swz(r, wch + 1)] = vB;
  {
    const u16* kn = K + base + (size_t)(64 + r) * 1024 + c0;
    kA = *(const bf16x8*)kn;
    kB = *(const bf16x8*)(kn + 8);
    const u16* vn = VT + vbase + (size_t)r * 2048 + 64 + c0;
    vA = *(const bf16x8*)vn;
    vB = *(const bf16x8*)(vn + 8);
  }

  const fp32x4 zero4 = {0.f, 0.f, 0.f, 0.f};
  fp32x4 onT[4];
#pragma unroll
  for (int df = 0; df < 4; df++) onT[df] = zero4;
  float mrun = -1e30f, lrun = 0.f;

  for (int kt = 0; kt < 32; ++kt) {
    __syncthreads();  // buf[kt&1] staged; prior reads of buf[(kt+1)&1] done
    if (kt < 31) {
      // stage tile kt+1 into the other buffer (overlaps compute across waves)
      u16* dK = sK[(kt + 1) & 1];
      u16* dV = sVT[(kt + 1) & 1];
      *(bf16x8*)&dK[swz(r, wch)] = kA;
      *(bf16x8*)&dK[swz(r, wch + 1)] = kB;
      *(bf16x8*)&dV[swz(r, wch)] = vA;
      *(bf16x8*)&dV[swz(r, wch + 1)] = vB;
      if (kt < 30) {  // issue loads for tile kt+2
        const u16* kn = K + base + (size_t)((kt + 2) * 64 + r) * 1024 + c0;
        kA = *(const bf16x8*)kn;
        kB = *(const bf16x8*)(kn + 8);
        const u16* vn = VT + vbase + (size_t)r * 2048 + (kt + 2) * 64 + c0;
        vA = *(const bf16x8*)vn;
        vB = *(const bf16x8*)(vn + 8);
      }
    }
    const u16* cK = sK[kt & 1];
    const u16* cV = sVT[kt & 1];

    fp32x4 sc[4];
    __builtin_amdgcn_s_setprio(1);
#pragma unroll
    for (int kk = 0; kk < 4; kk++) {
      fp32x4 a = zero4;
      bf16x8 kf0 = *(const bf16x8*)&cK[swz(kk * 16 + lr, hi)];
      bf16x8 kf1 = *(const bf16x8*)&cK[swz(kk * 16 + lr, 4 + hi)];
      a = __builtin_amdgcn_mfma_f32_16x16x32_bf16(kf0, qreg0, a, 0, 0, 0);
      a = __builtin_amdgcn_mfma_f32_16x16x32_bf16(kf1, qreg1, a, 0, 0, 0);
      sc[kk] = a;
    }
    __builtin_amdgcn_s_setprio(0);

    float m0 = fmaxf(fmaxf(sc[0][0], sc[0][1]), fmaxf(sc[0][2], sc[0][3]));
    float m1 = fmaxf(fmaxf(sc[1][0], sc[1][1]), fmaxf(sc[1][2], sc[1][3]));
    float m2 = fmaxf(fmaxf(sc[2][0], sc[2][1]), fmaxf(sc[2][2], sc[2][3]));
    float m3 = fmaxf(fmaxf(sc[3][0], sc[3][1]), fmaxf(sc[3][2], sc[3][3]));
    float mloc = fmaxf(fmaxf(m0, m1), fmaxf(m2, m3));
    mloc = fmaxf(mloc, __shfl_xor(mloc, 16));
    mloc = fmaxf(mloc, __shfl_xor(mloc, 32));
    if (!__all(mloc - mrun <= 11.0f)) {
      const float mnew = fmaxf(mrun, mloc);
      const float alpha = exp2f(mrun - mnew);
      lrun *= alpha;
#pragma unroll
      for (int df = 0; df < 4; df++) onT[df] *= alpha;
      mrun = mnew;
    }
#pragma unroll
    for (int kk = 0; kk < 4; kk++) {
      float p0 = exp2f(sc[kk][0] - mrun), p1 = exp2f(sc[kk][1] - mrun);
      float p2 = exp2f(sc[kk][2] - mrun), p3 = exp2f(sc[kk][3] - mrun);
      lrun += (p0 + p1) + (p2 + p3);
      uint2 pk = {cvt_pk_bf16(p0, p1), cvt_pk_bf16(p2, p3)};
      *(uint2*)&sQP[swz(qrow, 2 * kk + (hi >> 1)) + (hi & 1) * 4] = pk;
    }

    __builtin_amdgcn_s_setprio(1);
#pragma unroll
    for (int df = 0; df < 4; df++) {
#pragma unroll
      for (int ks = 0; ks < 2; ks++) {
        bf16x8 vf = *(const bf16x8*)&cV[swz(df * 16 + lr, ks * 4 + hi)];
        bf16x8 pf = *(const bf16x8*)&sQP[swz(qrow, ks * 4 + hi)];
        onT[df] = __builtin_amdgcn_mfma_f32_16x16x32_bf16(vf, pf, onT[df], 0, 0, 0);
      }
    }
    __builtin_amdgcn_s_setprio(0);
  }

  lrun += __shfl_xor(lrun, 16);
  lrun += __shfl_xor(lrun, 32);
  const float invl = 1.0f / lrun;
  u16* dst = O + base + (size_t)(qt * 64 + qrow) * 1024;
#pragma unroll
  for (int df = 0; df < 4; df++) {
    uint2 o2 = {cvt_pk_bf16(onT[df][0] * invl, onT[df][1] * invl),
                cvt_pk_bf16(onT[df][2] * invl, onT[df][3] * invl)};
    *(uint2*)&dst[df * 16 + hi * 4] = o2;
  }
}

extern "C" void kernel_launch(void* const* d_in, const int* in_sizes, int n_in,
                              void* d_out, int out_size, void* d_ws, size_t ws_size,
                              hipStream_t stream) {
  const float* x = (const float*)d_in[0];
  // d_in[1] = src_mask (unused by reference semantics)
  const float* wq = (const float*)d_in[2];
  const float* wk = (const float*)d_in[3];
  const float* wv = (const float*)d_in[4];
  const float* wo = (const float*)d_in[5];
  const float* w1 = (const float*)d_in[6];
  const float* b1 = (const float*)d_in[7];
  const float* w2 = (const float*)d_in[8];
  const float* b2 = (const float*)d_in[9];
  const float* g1 = (const float*)d_in[10];
  const float* be1 = (const float*)d_in[11];
  const float* g2 = (const float*)d_in[12];
  const float* be2 = (const float*)d_in[13];
  float* out = (float*)d_out;

  const size_t MB = 1024ull * 1024ull;
  char* ws = (char*)d_ws;
  if (ws_size < 136 * MB) return;  // fail loudly (output stays zero)

  u16* wqkv = (u16*)(ws + 0 * MB);  // [3072][1024]: wq | wk | wv contiguous
  u16* wob = (u16*)(ws + 6 * MB);
  u16* w1b = (u16*)(ws + 8 * MB);
  u16* w2b = (u16*)(ws + 16 * MB);
  u16* Qb = (u16*)(ws + 24 * MB);
  u16* Kb = (u16*)(ws + 40 * MB);
  u16* VTb = (u16*)(ws + 56 * MB);  // V written directly in VT layout by QKV
  u16* Ctx = (u16*)(ws + 72 * MB);
  u16* Hb = (u16*)(ws + 24 * MB);   // reuses Q/K/VT/Ctx (dead by FFN1)
  u16* Yb = (u16*)(ws + 88 * MB);
  u16* X2b = (u16*)(ws + 104 * MB); // bf16 residual state

  dim3 blk(256);

  // one dispatch converts all six weight tensors (dest is contiguous at ws+0)
  cvt_all<<<12288, blk, 0, stream>>>(wq, wk, wv, wo, w1, w2, (u16*)ws);

  ln_kernel<<<8192, blk, 0, stream>>>(x, Yb, g1, be1);

  // fused QKV; V-blocks transpose in-LDS and write VT directly (no vtrans)
  gemm_bt<4><<<dim3(24, 64), blk, 0, stream>>>(Yb, wqkv, Qb, nullptr, nullptr, nullptr,
                                               8192, 3072, 1024, Kb, VTb, nullptr);

  attn_kernel<<<dim3(32, 16, 4), blk, 0, stream>>>(Qb, Kb, VTb, Ctx);

  // Wo + residual(x fp32) -> X2 stored bf16
  gemm_bt<5><<<dim3(8, 64), blk, 0, stream>>>(Ctx, wob, X2b, nullptr, nullptr, x, 8192,
                                              1024, 1024, nullptr, nullptr, nullptr);

  ln_bf16_kernel<<<8192, blk, 0, stream>>>(X2b, Yb, g2, be2);

  gemm_bt<1><<<dim3(32, 64), blk, 0, stream>>>(Yb, w1b, Hb, nullptr, b1, nullptr, 8192,
                                               4096, 1024, nullptr, nullptr, nullptr);

  // FFN2: bias + bf16 residual (X2b) -> fp32 out
  gemm_bt<6><<<dim3(8, 64), blk, 0, stream>>>(Hb, w2b, nullptr, out, b2, nullptr, 8192,
                                              1024, 4096, nullptr, nullptr, X2b);
}

// Round 22
// 419.451 us; speedup vs baseline: 1.0058x; 1.0058x over previous
//
#include <hip/hip_runtime.h>
#include <hip/hip_bf16.h>

#define DEV static __device__ __forceinline__

typedef unsigned short u16;
typedef float fp32x4 __attribute__((ext_vector_type(4)));
typedef short bf16x8 __attribute__((ext_vector_type(8)));
typedef short bf16x4 __attribute__((ext_vector_type(4)));

DEV float bf2f(u16 u) { return __uint_as_float(((unsigned)u) << 16); }
DEV u16 f2bf(float f) {
  unsigned x = __float_as_uint(f);
  x += 0x7fffu + ((x >> 16) & 1u);
  return (u16)(x >> 16);
}

// packed f32x2 -> bf16x2 (low = a, high = b); no builtin on gfx950 (m240)
DEV unsigned cvt_pk_bf16(float a, float b) {
  unsigned r;
  asm("v_cvt_pk_bf16_f32 %0, %1, %2" : "=v"(r) : "v"(a), "v"(b));
  return r;
}

DEV void gload_lds16(const void* g, void* l) {
  __builtin_amdgcn_global_load_lds(
      (__attribute__((address_space(1))) void*)(unsigned long long)g,
      (__attribute__((address_space(3))) void*)(unsigned int)(unsigned long long)l,
      16, 0, 0);
}

// ---------------- fp32 -> bf16 convert: ALL weights in one dispatch ---------
__global__ __launch_bounds__(256) void cvt_all(
    const float* __restrict__ wq, const float* __restrict__ wk,
    const float* __restrict__ wv, const float* __restrict__ wo,
    const float* __restrict__ w1, const float* __restrict__ w2,
    u16* __restrict__ dst) {
  const size_t i = (size_t)blockIdx.x * 256 + threadIdx.x;  // vec4 index
  const size_t e = i * 4;                                   // element index
  const float* src;
  size_t off;
  const size_t M1 = 1u << 20;
  if (e < M1) { src = wq; off = e; }
  else if (e < 2 * M1) { src = wk; off = e - M1; }
  else if (e < 3 * M1) { src = wv; off = e - 2 * M1; }
  else if (e < 4 * M1) { src = wo; off = e - 3 * M1; }
  else if (e < 8 * M1) { src = w1; off = e - 4 * M1; }
  else { src = w2; off = e - 8 * M1; }
  const fp32x4 v = *(const fp32x4*)(src + off);
  bf16x4 o;
#pragma unroll
  for (int j = 0; j < 4; j++) o[j] = (short)f2bf(v[j]);
  ((bf16x4*)dst)[i] = o;
}

// ---------------- LayerNorm (ddof=1, eps added to std), fp32 in -> bf16 out --
__global__ __launch_bounds__(256) void ln_kernel(const float* __restrict__ x,
                                                 u16* __restrict__ y,
                                                 const float* __restrict__ gamma,
                                                 const float* __restrict__ beta) {
  const int row = blockIdx.x;
  const int t = threadIdx.x;
  const fp32x4 v = ((const fp32x4*)(x + (size_t)row * 1024))[t];
  float s = v[0] + v[1] + v[2] + v[3];
  float ss = v[0] * v[0] + v[1] * v[1] + v[2] * v[2] + v[3] * v[3];
#pragma unroll
  for (int o = 32; o > 0; o >>= 1) {
    s += __shfl_down(s, o);
    ss += __shfl_down(ss, o);
  }
  __shared__ float rs[4], rss[4];
  const int w = t >> 6;
  if ((t & 63) == 0) { rs[w] = s; rss[w] = ss; }
  __syncthreads();
  const float S = rs[0] + rs[1] + rs[2] + rs[3];
  const float SS = rss[0] + rss[1] + rss[2] + rss[3];
  const float mean = S * (1.0f / 1024.0f);
  const float var = fmaxf((SS - 1024.0f * mean * mean) * (1.0f / 1023.0f), 0.0f);
  const float sc = gamma[0] / (sqrtf(var) + 1e-6f);
  const float be = beta[0];
  bf16x4 o;
#pragma unroll
  for (int j = 0; j < 4; j++) o[j] = (short)f2bf((v[j] - mean) * sc + be);
  ((bf16x4*)(y + (size_t)row * 1024))[t] = o;
}

// ---------------- LayerNorm, bf16 in -> bf16 out (stats in fp32) ------------
__global__ __launch_bounds__(256) void ln_bf16_kernel(const u16* __restrict__ x,
                                                      u16* __restrict__ y,
                                                      const float* __restrict__ gamma,
                                                      const float* __restrict__ beta) {
  const int row = blockIdx.x;
  const int t = threadIdx.x;
  const bf16x4 vb = ((const bf16x4*)(x + (size_t)row * 1024))[t];
  float v0 = bf2f((u16)vb[0]), v1 = bf2f((u16)vb[1]);
  float v2 = bf2f((u16)vb[2]), v3 = bf2f((u16)vb[3]);
  float s = v0 + v1 + v2 + v3;
  float ss = v0 * v0 + v1 * v1 + v2 * v2 + v3 * v3;
#pragma unroll
  for (int o = 32; o > 0; o >>= 1) {
    s += __shfl_down(s, o);
    ss += __shfl_down(ss, o);
  }
  __shared__ float rs[4], rss[4];
  const int w = t >> 6;
  if ((t & 63) == 0) { rs[w] = s; rss[w] = ss; }
  __syncthreads();
  const float S = rs[0] + rs[1] + rs[2] + rs[3];
  const float SS = rss[0] + rss[1] + rss[2] + rss[3];
  const float mean = S * (1.0f / 1024.0f);
  const float var = fmaxf((SS - 1024.0f * mean * mean) * (1.0f / 1023.0f), 0.0f);
  const float sc = gamma[0] / (sqrtf(var) + 1e-6f);
  const float be = beta[0];
  bf16x4 o;
  o[0] = (short)f2bf((v0 - mean) * sc + be);
  o[1] = (short)f2bf((v1 - mean) * sc + be);
  o[2] = (short)f2bf((v2 - mean) * sc + be);
  o[3] = (short)f2bf((v3 - mean) * sc + be);
  ((bf16x4*)(y + (size_t)row * 1024))[t] = o;
}

// ---------------- GEMM: C[M,N] = A[M,K] @ W[N,K]^T (BK=64 m97 skeleton) -----
// BK=64 halves barrier-drain events vs BK=32 (R19 win). Frag reads use
// both-sides XOR involution (rule 21) -> 2-way = free.
// EPI: 1 = bias+relu -> bf16; 4 = fused QKV (Q,K direct; V -> VT layout);
//      5 = +fp32 resid -> bf16 store; 6 = bias + bf16 resid -> fp32 store
template <int EPI>
__global__ __launch_bounds__(256, 3) void gemm_bt(
    const u16* __restrict__ A, const u16* __restrict__ W, u16* __restrict__ Cb,
    float* __restrict__ Cf, const float* __restrict__ bias,
    const float* __restrict__ resid, int M, int N, int K,
    u16* __restrict__ CbK, u16* __restrict__ CbV, const u16* __restrict__ residB) {
  __shared__ __attribute__((aligned(16))) u16 sA[128 * 64];
  __shared__ __attribute__((aligned(16))) u16 sB[128 * 64];
  const int t = threadIdx.x;
  const int lane = t & 63;
  const int w = t >> 6;
  const int wr = (w >> 1) * 64;
  const int wc = (w & 1) * 64;
  const int lr = lane & 15;
  const int hi = lane >> 4;

  const int nwgx = gridDim.x;
  const int orig = blockIdx.y * nwgx + blockIdx.x;
  const int cpx = (nwgx * gridDim.y) >> 3;
  const int logical = (orig & 7) * cpx + (orig >> 3);
  const int bx = logical % nwgx, by = logical / nwgx;

  const int srow = t >> 3;
  const int lchunk = (t & 7) ^ (srow & 7);
  const u16* gA = A + (size_t)(by * 128 + srow) * K + lchunk * 8;
  const u16* gB = W + (size_t)(bx * 128 + srow) * K + lchunk * 8;
  const size_t rstep32 = (size_t)32 * K;
  u16* lA = &sA[t * 8];
  u16* lB = &sB[t * 8];

  const fp32x4 zero4 = {0.f, 0.f, 0.f, 0.f};
  fp32x4 acc[4][4];
#pragma unroll
  for (int i = 0; i < 4; i++)
#pragma unroll
    for (int j = 0; j < 4; j++) acc[i][j] = zero4;

  for (int k0 = 0; k0 < K; k0 += 64) {
#pragma unroll
    for (int p = 0; p < 4; p++) {
      gload_lds16(gA + p * rstep32, lA + p * 2048);
      gload_lds16(gB + p * rstep32, lB + p * 2048);
    }
    gA += 64;
    gB += 64;
    __syncthreads();
#pragma unroll
    for (int ks = 0; ks < 2; ks++) {
      const int fcA = ((ks * 4 + hi) ^ (lr & 7)) * 8;
      bf16x8 af[4], bfr[4];
#pragma unroll
      for (int i = 0; i < 4; i++)
        af[i] = *(const bf16x8*)&sA[(wr + i * 16 + lr) * 64 + fcA];
#pragma unroll
      for (int j = 0; j < 4; j++)
        bfr[j] = *(const bf16x8*)&sB[(wc + j * 16 + lr) * 64 + fcA];
#pragma unroll
      for (int i = 0; i < 4; i++)
#pragma unroll
        for (int j = 0; j < 4; j++)
          acc[i][j] =
              __builtin_amdgcn_mfma_f32_16x16x32_bf16(af[i], bfr[j], acc[i][j], 0, 0, 0);
    }
    __syncthreads();
  }

  const int row0 = by * 128 + wr + hi * 4;
  const int col0 = bx * 128 + wc + lr;

  if constexpr (EPI == 4) {
    if (col0 < 2048) {  // Q or K block: direct bf16 store
      u16* qkvDst = (col0 >> 10) ? CbK : Cb;
      const int colL0 = col0 & 1023;
#pragma unroll
      for (int i = 0; i < 4; i++)
#pragma unroll
        for (int r = 0; r < 4; r++) {
          const size_t row = (size_t)(row0 + i * 16 + r);
#pragma unroll
          for (int j = 0; j < 4; j++)
            qkvDst[row * 1024 + colL0 + j * 16] = f2bf(acc[i][j][r]);
        }
    } else {
      // V block: per-wave 64x64 in-LDS transpose -> VT[(b*16+h)*64+d][s]
      __shared__ __attribute__((aligned(16))) u16 sT[2][64 * 72];
#pragma unroll
      for (int ph = 0; ph < 2; ++ph) {
        __syncthreads();
        if ((w >> 1) == ph) {
          u16* R = sT[w & 1];
#pragma unroll
          for (int j = 0; j < 4; j++) {
            const int ci = j * 16 + lr;
            const int X = (ci ^ (ci >> 3)) & 7;
#pragma unroll
            for (int i = 0; i < 4; i++)
#pragma unroll
              for (int r = 0; r < 4; r++) {
                const int ri = i * 16 + hi * 4 + r;
                R[ci * 72 + ((((ri >> 3) ^ X) << 3) | (ri & 7))] =
                    f2bf(acc[i][j][r]);
              }
          }
        }
        __syncthreads();
        if ((w >> 1) == ph) {
          const u16* R = sT[w & 1];
          const int ci = lane;
          const int X = (ci ^ (ci >> 3)) & 7;
          const int h = (bx - 16) * 2 + (w & 1);
          const int bidx = by >> 4;
          const int sb_base = (by & 15) * 128 + (w >> 1) * 64;
          u16* vdst = CbV + ((size_t)((bidx * 16 + h) * 64 + ci)) * 2048 + sb_base;
#pragma unroll
          for (int ch = 0; ch < 8; ch++) {
            bf16x8 vv = *(const bf16x8*)&R[ci * 72 + ((ch ^ X) << 3)];
            *(bf16x8*)(vdst + ch * 8) = vv;
          }
        }
      }
    }
    return;
  }

  float bj[4] = {0.f, 0.f, 0.f, 0.f};
  if (EPI == 1 || EPI == 6) {
#pragma unroll
    for (int j = 0; j < 4; j++) bj[j] = bias[col0 + j * 16];
  }
#pragma unroll
  for (int i = 0; i < 4; i++) {
#pragma unroll
    for (int r = 0; r < 4; r++) {
      const size_t row = (size_t)(row0 + i * 16 + r);
#pragma unroll
      for (int j = 0; j < 4; j++) {
        const int col = col0 + j * 16;
        float v = acc[i][j][r];
        if (EPI == 1) {
          v = fmaxf(v + bj[j], 0.f);
          Cb[row * N + col] = f2bf(v);
        } else if (EPI == 5) {
          v += resid[row * N + col];
          Cb[row * N + col] = f2bf(v);
        } else if (EPI == 6) {
          v += bj[j] + bf2f(residB[row * N + col]);
          Cf[row * N + col] = v;
        }
      }
    }
  }
}

// ---------------- Flash attention (64 q-rows/block, 64-k tiles) -------------
// R20-proven config (reverted from R21 dbuf: residency > barrier count —
// LDS 24.6->40.9KB cut occupancy 44->37% and cost +3us). 2048 blocks,
// [64][64] LDS + chunk-XOR swizzle, exp2 softmax, cvt_pk, defer-max,
// setprio, XCD swizzle, deferred lrun reduction.
DEV int swz(int row, int chunk) { return row * 64 + ((chunk ^ (row & 7)) << 3); }

__global__ __launch_bounds__(256, 2) void attn_kernel(const u16* __restrict__ Q,
                                                      const u16* __restrict__ K,
                                                      const u16* __restrict__ VT,
                                                      u16* __restrict__ O) {
  const int orig = blockIdx.x + 32 * (blockIdx.y + 16 * blockIdx.z);
  const int logical = (orig & 7) * 256 + (orig >> 3);
  const int qt = logical & 31;
  const int h = (logical >> 5) & 15;
  const int b = logical >> 9;

  const int t = threadIdx.x, lane = t & 63, w = t >> 6;
  const int lr = lane & 15, hi = lane >> 4;

  __shared__ u16 sK[64 * 64];
  __shared__ u16 sVT[64 * 64];
  __shared__ u16 sQP[64 * 64];

  const size_t base = ((size_t)b * 2048) * 1024 + (size_t)h * 64;
  const size_t vbase = (((size_t)b * 16 + h) * 64) * 2048;
  const int r = t >> 2, c0 = (t & 3) * 16;
  const int wch = (t & 3) * 2;

  {
    const float qs = 0.125f * 1.44269504f;
    const u16* src = Q + base + (size_t)(qt * 64 + r) * 1024 + c0;
    bf16x8 u0 = *(const bf16x8*)src;
    bf16x8 u1 = *(const bf16x8*)(src + 8);
    union { unsigned u[4]; bf16x8 v; } q0, q1;
#pragma unroll
    for (int j = 0; j < 4; j++)
      q0.u[j] = cvt_pk_bf16(bf2f((u16)u0[2 * j]) * qs, bf2f((u16)u0[2 * j + 1]) * qs);
#pragma unroll
    for (int j = 0; j < 4; j++)
      q1.u[j] = cvt_pk_bf16(bf2f((u16)u1[2 * j]) * qs, bf2f((u16)u1[2 * j + 1]) * qs);
    *(bf16x8*)&sQP[swz(r, wch)] = q0.v;
    *(bf16x8*)&sQP[swz(r, wch + 1)] = q1.v;
  }
  __syncthreads();
  const int qrow = w * 16 + lr;
  bf16x8 qreg0 = *(const bf16x8*)&sQP[swz(qrow, hi)];
  bf16x8 qreg1 = *(const bf16x8*)&sQP[swz(qrow, 4 + hi)];

  bf16x8 kA, kB, vA, vB;
  {
    const u16* ks = K + base + (size_t)r * 1024 + c0;
    kA = *(const bf16x8*)ks;
    kB = *(const bf16x8*)(ks + 8);
    const u16* vs = VT + vbase + (size_t)r * 2048 + c0;
    vA = *(const bf16x8*)vs;
    vB = *(const bf16x8*)(vs + 8);
  }

  const fp32x4 zero4 = {0.f, 0.f, 0.f, 0.f};
  fp32x4 onT[4];
#pragma unroll
  for (int df = 0; df < 4; df++) onT[df] = zero4;
  float mrun = -1e30f, lrun = 0.f;

  for (int kt = 0; kt < 32; ++kt) {
    __syncthreads();
    *(bf16x8*)&sK[swz(r, wch)] = kA;
    *(bf16x8*)&sK[swz(r, wch + 1)] = kB;
    *(bf16x8*)&sVT[swz(r, wch)] = vA;
    *(bf16x8*)&sVT[swz(r, wch + 1)] = vB;
    __syncthreads();
    if (kt < 31) {
      const u16* kn = K + base + (size_t)((kt + 1) * 64 + r) * 1024 + c0;
      kA = *(const bf16x8*)kn;
      kB = *(const bf16x8*)(kn + 8);
      const u16* vn = VT + vbase + (size_t)r * 2048 + (kt + 1) * 64 + c0;
      vA = *(const bf16x8*)vn;
      vB = *(const bf16x8*)(vn + 8);
    }

    fp32x4 sc[4];
    __builtin_amdgcn_s_setprio(1);
#pragma unroll
    for (int kk = 0; kk < 4; kk++) {
      fp32x4 a = zero4;
      bf16x8 kf0 = *(const bf16x8*)&sK[swz(kk * 16 + lr, hi)];
      bf16x8 kf1 = *(const bf16x8*)&sK[swz(kk * 16 + lr, 4 + hi)];
      a = __builtin_amdgcn_mfma_f32_16x16x32_bf16(kf0, qreg0, a, 0, 0, 0);
      a = __builtin_amdgcn_mfma_f32_16x16x32_bf16(kf1, qreg1, a, 0, 0, 0);
      sc[kk] = a;
    }
    __builtin_amdgcn_s_setprio(0);

    float m0 = fmaxf(fmaxf(sc[0][0], sc[0][1]), fmaxf(sc[0][2], sc[0][3]));
    float m1 = fmaxf(fmaxf(sc[1][0], sc[1][1]), fmaxf(sc[1][2], sc[1][3]));
    float m2 = fmaxf(fmaxf(sc[2][0], sc[2][1]), fmaxf(sc[2][2], sc[2][3]));
    float m3 = fmaxf(fmaxf(sc[3][0], sc[3][1]), fmaxf(sc[3][2], sc[3][3]));
    float mloc = fmaxf(fmaxf(m0, m1), fmaxf(m2, m3));
    mloc = fmaxf(mloc, __shfl_xor(mloc, 16));
    mloc = fmaxf(mloc, __shfl_xor(mloc, 32));
    if (!__all(mloc - mrun <= 11.0f)) {
      const float mnew = fmaxf(mrun, mloc);
      const float alpha = exp2f(mrun - mnew);
      lrun *= alpha;
#pragma unroll
      for (int df = 0; df < 4; df++) onT[df] *= alpha;
      mrun = mnew;
    }
#pragma unroll
    for (int kk = 0; kk < 4; kk++) {
      float p0 = exp2f(sc[kk][0] - mrun), p1 = exp2f(sc[kk][1] - mrun);
      float p2 = exp2f(sc[kk][2] - mrun), p3 = exp2f(sc[kk][3] - mrun);
      lrun += (p0 + p1) + (p2 + p3);
      uint2 pk = {cvt_pk_bf16(p0, p1), cvt_pk_bf16(p2, p3)};
      *(uint2*)&sQP[swz(qrow, 2 * kk + (hi >> 1)) + (hi & 1) * 4] = pk;
    }

    __builtin_amdgcn_s_setprio(1);
#pragma unroll
    for (int df = 0; df < 4; df++) {
#pragma unroll
      for (int ks = 0; ks < 2; ks++) {
        bf16x8 vf = *(const bf16x8*)&sVT[swz(df * 16 + lr, ks * 4 + hi)];
        bf16x8 pf = *(const bf16x8*)&sQP[swz(qrow, ks * 4 + hi)];
        onT[df] = __builtin_amdgcn_mfma_f32_16x16x32_bf16(vf, pf, onT[df], 0, 0, 0);
      }
    }
    __builtin_amdgcn_s_setprio(0);
  }

  lrun += __shfl_xor(lrun, 16);
  lrun += __shfl_xor(lrun, 32);
  const float invl = 1.0f / lrun;
  u16* dst = O + base + (size_t)(qt * 64 + qrow) * 1024;
#pragma unroll
  for (int df = 0; df < 4; df++) {
    uint2 o2 = {cvt_pk_bf16(onT[df][0] * invl, onT[df][1] * invl),
                cvt_pk_bf16(onT[df][2] * invl, onT[df][3] * invl)};
    *(uint2*)&dst[df * 16 + hi * 4] = o2;
  }
}

extern "C" void kernel_launch(void* const* d_in, const int* in_sizes, int n_in,
                              void* d_out, int out_size, void* d_ws, size_t ws_size,
                              hipStream_t stream) {
  const float* x = (const float*)d_in[0];
  // d_in[1] = src_mask (unused by reference semantics)
  const float* wq = (const float*)d_in[2];
  const float* wk = (const float*)d_in[3];
  const float* wv = (const float*)d_in[4];
  const float* wo = (const float*)d_in[5];
  const float* w1 = (const float*)d_in[6];
  const float* b1 = (const float*)d_in[7];
  const float* w2 = (const float*)d_in[8];
  const float* b2 = (const float*)d_in[9];
  const float* g1 = (const float*)d_in[10];
  const float* be1 = (const float*)d_in[11];
  const float* g2 = (const float*)d_in[12];
  const float* be2 = (const float*)d_in[13];
  float* out = (float*)d_out;

  const size_t MB = 1024ull * 1024ull;
  char* ws = (char*)d_ws;
  if (ws_size < 136 * MB) return;  // fail loudly (output stays zero)

  u16* wqkv = (u16*)(ws + 0 * MB);  // [3072][1024]: wq | wk | wv contiguous
  u16* wob = (u16*)(ws + 6 * MB);
  u16* w1b = (u16*)(ws + 8 * MB);
  u16* w2b = (u16*)(ws + 16 * MB);
  u16* Qb = (u16*)(ws + 24 * MB);
  u16* Kb = (u16*)(ws + 40 * MB);
  u16* VTb = (u16*)(ws + 56 * MB);  // V written directly in VT layout by QKV
  u16* Ctx = (u16*)(ws + 72 * MB);
  u16* Hb = (u16*)(ws + 24 * MB);   // reuses Q/K/VT/Ctx (dead by FFN1)
  u16* Yb = (u16*)(ws + 88 * MB);
  u16* X2b = (u16*)(ws + 104 * MB); // bf16 residual state

  dim3 blk(256);

  // one dispatch converts all six weight tensors (dest is contiguous at ws+0)
  cvt_all<<<12288, blk, 0, stream>>>(wq, wk, wv, wo, w1, w2, (u16*)ws);

  ln_kernel<<<8192, blk, 0, stream>>>(x, Yb, g1, be1);

  // fused QKV; V-blocks transpose in-LDS and write VT directly (no vtrans)
  gemm_bt<4><<<dim3(24, 64), blk, 0, stream>>>(Yb, wqkv, Qb, nullptr, nullptr, nullptr,
                                               8192, 3072, 1024, Kb, VTb, nullptr);

  attn_kernel<<<dim3(32, 16, 4), blk, 0, stream>>>(Qb, Kb, VTb, Ctx);

  // Wo + residual(x fp32) -> X2 stored bf16
  gemm_bt<5><<<dim3(8, 64), blk, 0, stream>>>(Ctx, wob, X2b, nullptr, nullptr, x, 8192,
                                              1024, 1024, nullptr, nullptr, nullptr);

  ln_bf16_kernel<<<8192, blk, 0, stream>>>(X2b, Yb, g2, be2);

  gemm_bt<1><<<dim3(32, 64), blk, 0, stream>>>(Yb, w1b, Hb, nullptr, b1, nullptr, 8192,
                                               4096, 1024, nullptr, nullptr, nullptr);

  // FFN2: bias + bf16 residual (X2b) -> fp32 out
  gemm_bt<6><<<dim3(8, 64), blk, 0, stream>>>(Hb, w2b, nullptr, out, b2, nullptr, 8192,
                                              1024, 4096, nullptr, nullptr, X2b);
}